// Round 10
// baseline (40.807 us; speedup 1.0000x reference)
//
#include <hip/hip_runtime.h>
#include <math.h>
#include <float.h>

#define BATCH 1024
#define DIM 128
#define EPSV 1e-12f
#define MARGIN 0.5f
#define INTRA_MARGIN 0.1f
#define LAMDA 0.5f

typedef __attribute__((ext_vector_type(8))) short s16x8;   // 8 bf16 (4 VGPRs)
typedef __attribute__((ext_vector_type(4))) float f32x4;   // MFMA C/D

__device__ __forceinline__ ushort f2bf(float f) {          // RNE fp32 -> bf16
    unsigned u = __float_as_uint(f);
    return (ushort)((u + 0x7fffu + ((u >> 16) & 1u)) >> 16);
}

// ---------------- Kernel A: feat -> bf16 + fp32 row norms ----------------
// 128 blocks x 256 threads; 16 threads per row, 8 floats per thread.
__global__ __launch_bounds__(256) void prep_kernel(
    const float* __restrict__ feat, ushort* __restrict__ bhi,
    float* __restrict__ norm2)
{
    const int t = threadIdx.x;
    const int gt  = blockIdx.x * 256 + t;  // 0..32767
    const int row = gt >> 4, seg = gt & 15;
    const float4* p = reinterpret_cast<const float4*>(feat + (size_t)row * DIM + seg * 8);
    const float4 a = p[0], b = p[1];
    const float v[8] = {a.x, a.y, a.z, a.w, b.x, b.y, b.z, b.w};
    ushort h[8];
    float n = 0.0f;
    #pragma unroll
    for (int e = 0; e < 8; ++e) {
        h[e] = f2bf(v[e]);
        n = fmaf(v[e], v[e], n);
    }
    uint4 uh;
    uh.x = (uint)h[0] | ((uint)h[1] << 16); uh.y = (uint)h[2] | ((uint)h[3] << 16);
    uh.z = (uint)h[4] | ((uint)h[5] << 16); uh.w = (uint)h[6] | ((uint)h[7] << 16);
    *reinterpret_cast<uint4*>(bhi + (size_t)row * DIM + seg * 8) = uh;
    n += __shfl_xor(n, 1); n += __shfl_xor(n, 2);
    n += __shfl_xor(n, 4); n += __shfl_xor(n, 8);
    if ((t & 15) == 0) norm2[row] = n;
}

// ---------------- Kernel B: MFMA gram + selection + intra; writes partial[rg] ----------------
// 128 blocks x 512 threads, grid-stride over 256 rowgroups (2 per block).
// Rowgroup = 8 rows (one half) x ALL 1024 cols; wave w covers cols [w*128, +128)
// as 8 subtiles of 16. MFMA A-fragment duplicates rows (l15&7); C rows 8..15 ignored.
__global__ __launch_bounds__(512, 2) void gemm_kernel(
    const ushort* __restrict__ bhi, const float* __restrict__ norm2,
    const float* __restrict__ feat,
    const int* __restrict__ label1, const int* __restrict__ label2,
    float* __restrict__ partial)
{
    const int t = threadIdx.x;
    const int w = t >> 6, lane = t & 63;
    const int l15 = lane & 15, kg = lane >> 4;

    __shared__ float L_pv[16][8]; __shared__ int L_pj[16][8];
    __shared__ float L_nv[16][8]; __shared__ int L_nj[16][8];
    __shared__ int s_pp[8], s_pn[8];
    __shared__ float s_fp[8], s_cn[8];
    __shared__ float ls[8];

    for (int rg = blockIdx.x; rg < 256; rg += 128) {
        __syncthreads();                     // guard shared reuse across iterations

        const int half  = rg >> 7;               // 128 rowgroups per half
        const int arow0 = (rg & 127) * 8;        // row base within half
        const int aglob0 = half * BATCH + arow0; // row base in 2048-row arrays
        const int bglob0 = (half ^ 1) * BATCH;

        const int* labA = half ? label2 : label1;
        const int* labB = half ? label1 : label2;

        // ---- addresses ----
        const size_t abase = (size_t)(aglob0 + (l15 & 7)) * DIM;
        int jcol[8]; size_t bbase[8];
        #pragma unroll
        for (int s = 0; s < 8; ++s) {
            jcol[s]  = w * 128 + s * 16 + l15;
            bbase[s] = (size_t)(bglob0 + jcol[s]) * DIM;
        }

        // ---- fragment loads (deep prefetch) ----
        s16x8 ah[4], bh[4][8];
        #pragma unroll
        for (int kt = 0; kt < 4; ++kt) {
            const int koff = kt * 32 + kg * 8;
            ah[kt] = *reinterpret_cast<const s16x8*>(bhi + abase + koff);
            #pragma unroll
            for (int s = 0; s < 8; ++s)
                bh[kt][s] = *reinterpret_cast<const s16x8*>(bhi + bbase[s] + koff);
        }

        // ---- scalar-side loads ----
        float nb[8]; int lb[8];
        #pragma unroll
        for (int s = 0; s < 8; ++s) {
            nb[s] = norm2[bglob0 + jcol[s]];
            lb[s] = labB[jcol[s]];
        }
        float na[4]; int la[4];
        #pragma unroll
        for (int r = 0; r < 4; ++r) {
            const int rr = (kg * 4 + r) & 7;
            na[r] = norm2[aglob0 + rr];
            la[r] = labA[arow0 + rr];
        }

        // ---- MFMA accumulation ----
        f32x4 acc[8];
        #pragma unroll
        for (int s = 0; s < 8; ++s) acc[s] = (f32x4){0.f, 0.f, 0.f, 0.f};
        #pragma unroll
        for (int kt = 0; kt < 4; ++kt) {
            #pragma unroll
            for (int s = 0; s < 8; ++s)
                acc[s] = __builtin_amdgcn_mfma_f32_16x16x32_bf16(ah[kt], bh[kt][s], acc[s], 0, 0, 0);
        }

        // ---- selection in d^2 domain; C/D layout: col=l15, row=kg*4+reg ----
        float bpv[4], bnv[4]; int bpj[4], bnj[4];
        #pragma unroll
        for (int r = 0; r < 4; ++r) { bpv[r] = -1.0f; bpj[r] = 0x7fffffff; bnv[r] = FLT_MAX; bnj[r] = 0x7fffffff; }

        #pragma unroll
        for (int s = 0; s < 8; ++s) {
            #pragma unroll
            for (int r = 0; r < 4; ++r) {
                const float d2 = fmaxf(na[r] + nb[s] - 2.0f * acc[s][r], 0.0f);
                const bool same = (la[r] == lb[s]);
                const float pv = same ? d2 : 0.0f;
                const float nv = same ? FLT_MAX : d2;
                // jcol ascending in s -> strict compares keep first occurrence
                if (pv > bpv[r]) { bpv[r] = pv; bpj[r] = jcol[s]; }
                if (nv < bnv[r]) { bnv[r] = nv; bnj[r] = jcol[s]; }
            }
        }

        // reduce across the 16 lanes of each row group (masks < 16 keep kg fixed)
        #pragma unroll
        for (int r = 0; r < 4; ++r) {
            #pragma unroll
            for (int m = 8; m > 0; m >>= 1) {
                const float opv = __shfl_xor(bpv[r], m); const int opj = __shfl_xor(bpj[r], m);
                if (opv > bpv[r] || (opv == bpv[r] && opj < bpj[r])) { bpv[r] = opv; bpj[r] = opj; }
                const float onv = __shfl_xor(bnv[r], m); const int onj = __shfl_xor(bnj[r], m);
                if (onv < bnv[r] || (onv == bnv[r] && onj < bnj[r])) { bnv[r] = onv; bnj[r] = onj; }
            }
        }

        // ---- cross-wave combine: 16 C-rows (8 real) x 8 col-chunks ----
        if (l15 == 0) {
            #pragma unroll
            for (int r = 0; r < 4; ++r) {
                const int rib = kg * 4 + r;
                L_pv[rib][w] = bpv[r]; L_pj[rib][w] = bpj[r];
                L_nv[rib][w] = bnv[r]; L_nj[rib][w] = bnj[r];
            }
        }
        __syncthreads();

        if (t < 8) {            // only the 8 real rows
            float pv = -1.0f; int pj = 0x7fffffff; float nv = FLT_MAX; int nj = 0x7fffffff;
            #pragma unroll
            for (int c = 0; c < 8; ++c) {   // ascending col ranges -> tie keeps first
                const float v1 = L_pv[t][c]; const int j1 = L_pj[t][c];
                if (v1 > pv || (v1 == pv && j1 < pj)) { pv = v1; pj = j1; }
                const float v2 = L_nv[t][c]; const int j2 = L_nj[t][c];
                if (v2 < nv || (v2 == nv && j2 < nj)) { nv = v2; nj = j2; }
            }
            s_pp[t] = pj > (BATCH - 1) ? (BATCH - 1) : pj;
            s_pn[t] = nj > (BATCH - 1) ? (BATCH - 1) : nj;
            s_fp[t] = (pv > 0.0f) ? sqrtf(pv + EPSV) : 0.0f;   // no-positive row -> 0
            s_cn[t] = sqrtf(nv + EPSV);
        }
        __syncthreads();

        // ---- intra distances (exact fp32): 8 rows x 16 lanes ----
        if (t < 128) {
            const int g = t >> 4, sl = t & 15;
            const float* fB = feat + (size_t)(half ^ 1) * BATCH * DIM;  // b-side = f_intra
            const float4* x = reinterpret_cast<const float4*>(fB + (size_t)s_pp[g] * DIM + sl * 8);
            const float4* y = reinterpret_cast<const float4*>(fB + (size_t)s_pn[g] * DIM + sl * 8);
            const float4 x0 = x[0], x1 = x[1], y0 = y[0], y1 = y[1];
            float d, d2;
            d = x0.x - y0.x; d2  = d * d;  d = x0.y - y0.y; d2 += d * d;
            d = x0.z - y0.z; d2 += d * d;  d = x0.w - y0.w; d2 += d * d;
            d = x1.x - y1.x; d2 += d * d;  d = x1.y - y1.y; d2 += d * d;
            d = x1.z - y1.z; d2 += d * d;  d = x1.w - y1.w; d2 += d * d;
            d2 += __shfl_xor(d2, 1); d2 += __shfl_xor(d2, 2);
            d2 += __shfl_xor(d2, 4); d2 += __shfl_xor(d2, 8);
            if (sl == 0) {
                const float gd = sqrtf(d2 + EPSV);
                const float loss = fmaxf(s_fp[g] - s_cn[g] + MARGIN, 0.0f)
                                 + LAMDA * fmaxf(INTRA_MARGIN - gd, 0.0f);
                ls[g] = loss * (1.0f / (float)BATCH);
            }
        }
        __syncthreads();

        if (t == 0) {
            float s = 0.0f;
            #pragma unroll
            for (int i = 0; i < 8; ++i) s += ls[i];
            partial[rg] = s;
        }
    }
}

// ---------------- Kernel C: deterministic reduce of 256 partials ----------------
__global__ __launch_bounds__(256) void reduce_kernel(
    const float* __restrict__ partial, float* __restrict__ out)
{
    const int t = threadIdx.x;
    float s = partial[t];
    #pragma unroll
    for (int m = 32; m > 0; m >>= 1) s += __shfl_down(s, m);
    __shared__ float ws4[4];
    if ((t & 63) == 0) ws4[t >> 6] = s;
    __syncthreads();
    if (t == 0) out[0] = ws4[0] + ws4[1] + ws4[2] + ws4[3];
}

extern "C" void kernel_launch(void* const* d_in, const int* in_sizes, int n_in,
                              void* d_out, int out_size, void* d_ws, size_t ws_size,
                              hipStream_t stream) {
    const float* feat   = (const float*)d_in[0];
    const int*   label1 = (const int*)d_in[1];
    const int*   label2 = (const int*)d_in[2];
    float* out = (float*)d_out;

    char* ws = (char*)d_ws;
    float*  partial = (float*)(ws);                        // 1 KB
    ushort* bhi     = (ushort*)(ws + 4096);                // 512 KB
    float*  norm2   = (float*)(ws + 4096 + 512 * 1024);    // 8 KB

    prep_kernel<<<dim3(128), dim3(256), 0, stream>>>(feat, bhi, norm2);
    gemm_kernel<<<dim3(128), dim3(512), 0, stream>>>(
        bhi, norm2, feat, label1, label2, partial);
    reduce_kernel<<<dim3(1), dim3(256), 0, stream>>>(partial, out);
}

// Round 11
// 23.835 us; speedup vs baseline: 1.7121x; 1.7121x over previous
//
#include <hip/hip_runtime.h>
#include <math.h>
#include <float.h>

#define BATCH 1024
#define DIM 128
#define EPSV 1e-12f
#define MARGIN 0.5f
#define INTRA_MARGIN 0.1f
#define LAMDA 0.5f

typedef __attribute__((ext_vector_type(8))) short s16x8;   // 8 bf16 (4 VGPRs)
typedef __attribute__((ext_vector_type(4))) float f32x4;   // MFMA C/D

__device__ __forceinline__ ushort f2bf(float f) {          // RNE fp32 -> bf16
    unsigned u = __float_as_uint(f);
    return (ushort)((u + 0x7fffu + ((u >> 16) & 1u)) >> 16);
}

// async global->LDS, 16B per lane, fire-and-forget (drained by vmcnt/syncthreads)
__device__ __forceinline__ void gl_lds16(const void* g, void* l) {
    __builtin_amdgcn_global_load_lds(
        (const __attribute__((address_space(1))) unsigned int*)g,
        (__attribute__((address_space(3))) unsigned int*)l,
        16, 0, 0);
}

// ---------------- Kernel A: feat -> bf16 (XOR-swizzled layout) + fp32 row norms ----------
// Swizzle: 16B chunk j of row r is stored at chunk index (j ^ (r&7)) within the row.
// 128 blocks x 256 threads; 16 threads per row, 8 floats (= one 16B bf16 chunk) each.
__global__ __launch_bounds__(256) void prep_kernel(
    const float* __restrict__ feat, ushort* __restrict__ bhi,
    float* __restrict__ norm2)
{
    const int t = threadIdx.x;
    const int gt  = blockIdx.x * 256 + t;  // 0..32767
    const int row = gt >> 4, seg = gt & 15;
    const float4* p = reinterpret_cast<const float4*>(feat + (size_t)row * DIM + seg * 8);
    const float4 a = p[0], b = p[1];
    const float v[8] = {a.x, a.y, a.z, a.w, b.x, b.y, b.z, b.w};
    ushort h[8];
    float n = 0.0f;
    #pragma unroll
    for (int e = 0; e < 8; ++e) {
        h[e] = f2bf(v[e]);
        n = fmaf(v[e], v[e], n);
    }
    uint4 uh;
    uh.x = (uint)h[0] | ((uint)h[1] << 16); uh.y = (uint)h[2] | ((uint)h[3] << 16);
    uh.z = (uint)h[4] | ((uint)h[5] << 16); uh.w = (uint)h[6] | ((uint)h[7] << 16);
    reinterpret_cast<uint4*>(bhi)[row * 16 + (seg ^ (row & 7))] = uh;   // swizzled chunk
    n += __shfl_xor(n, 1); n += __shfl_xor(n, 2);
    n += __shfl_xor(n, 4); n += __shfl_xor(n, 8);
    if ((t & 15) == 0) norm2[row] = n;
}

// ---------------- Kernel B: LDS-staged MFMA gram + selection -> cand ----------------
// 512 blocks x 512 threads (2 blocks/CU). Block (RG,q) = 16 rows x 256 cols (q-th chunk).
// B-panel (64 KB) staged via global_load_lds (linear copy of pre-swizzled bhi);
// ds_read_b128 fragment reads apply the same XOR -> conflict-free.
__global__ __launch_bounds__(512) void gemm_kernel(
    const ushort* __restrict__ bhi, const float* __restrict__ norm2,
    const int* __restrict__ label1, const int* __restrict__ label2,
    float4* __restrict__ cand)
{
    __shared__ ushort Blds[256 * DIM];     // 64 KB, swizzled same as bhi

    const int bid  = blockIdx.x;
    const int RG   = bid >> 2;             // rowgroup 0..127 (16 rows each)
    const int q    = bid & 3;              // col chunk (256 cols)
    const int half = RG >> 6;
    const int arow0  = (RG & 63) * 16;
    const int aglob0 = half * BATCH + arow0;
    const int bglob0 = (half ^ 1) * BATCH;

    const int t = threadIdx.x;
    const int w = t >> 6, lane = t & 63;
    const int l15 = lane & 15, kg = lane >> 4;

    const int* labA = half ? label2 : label1;
    const int* labB = half ? label1 : label2;

    // ---- B staging: 64 KB = 64 segments of 1 KB; wave w DMAs segments {i*8+w} ----
    const char* bbytes = reinterpret_cast<const char*>(bhi);
    char* lbytes = reinterpret_cast<char*>(Blds);
    const size_t Bbase = (size_t)(bglob0 + q * 256) * 256;   // byte offset of panel
    #pragma unroll
    for (int i = 0; i < 8; ++i) {
        const int o = (i * 8 + w) * 1024 + lane * 16;
        gl_lds16(bbytes + Bbase + o, lbytes + o);
    }

    // ---- A fragments straight from global (swizzled addresses), before the barrier ----
    s16x8 ah[4];
    const size_t abase = (size_t)(aglob0 + l15) * DIM;       // ushort index
    #pragma unroll
    for (int kt = 0; kt < 4; ++kt) {
        const int kh = (kt * 32 + kg * 8) ^ ((l15 & 7) << 3);
        ah[kt] = *reinterpret_cast<const s16x8*>(bhi + abase + kh);
    }

    // ---- scalar-side loads (complete under the staging latency) ----
    int jloc[2], jcol[2]; float nb[2]; int lb[2];
    #pragma unroll
    for (int s = 0; s < 2; ++s) {
        jloc[s] = w * 32 + s * 16 + l15;
        jcol[s] = q * 256 + jloc[s];
        nb[s] = norm2[bglob0 + jcol[s]];
        lb[s] = labB[jcol[s]];
    }
    float na[4]; int la[4];
    #pragma unroll
    for (int r = 0; r < 4; ++r) {
        na[r] = norm2[aglob0 + kg * 4 + r];
        la[r] = labA[arow0 + kg * 4 + r];
    }

    __syncthreads();    // drains vmcnt (DMA + ah) and barriers all waves

    // ---- MFMA from LDS ----
    f32x4 acc[2];
    acc[0] = (f32x4){0.f, 0.f, 0.f, 0.f};
    acc[1] = (f32x4){0.f, 0.f, 0.f, 0.f};
    #pragma unroll
    for (int kt = 0; kt < 4; ++kt) {
        #pragma unroll
        for (int s = 0; s < 2; ++s) {
            const int c = jloc[s];
            const int kh = (kt * 32 + kg * 8) ^ ((c & 7) << 3);
            const s16x8 bh = *reinterpret_cast<const s16x8*>(Blds + c * DIM + kh);
            acc[s] = __builtin_amdgcn_mfma_f32_16x16x32_bf16(ah[kt], bh, acc[s], 0, 0, 0);
        }
    }

    // ---- selection in d^2 domain; C/D layout: col=l15, row=kg*4+reg ----
    float bpv[4], bnv[4]; int bpj[4], bnj[4];
    #pragma unroll
    for (int r = 0; r < 4; ++r) { bpv[r] = -1.0f; bpj[r] = 0x7fffffff; bnv[r] = FLT_MAX; bnj[r] = 0x7fffffff; }

    #pragma unroll
    for (int s = 0; s < 2; ++s) {
        #pragma unroll
        for (int r = 0; r < 4; ++r) {
            const float d2 = fmaxf(na[r] + nb[s] - 2.0f * acc[s][r], 0.0f);
            const bool same = (la[r] == lb[s]);
            const float pv = same ? d2 : 0.0f;
            const float nv = same ? FLT_MAX : d2;
            // jcol ascending in s -> strict compares keep first occurrence
            if (pv > bpv[r]) { bpv[r] = pv; bpj[r] = jcol[s]; }
            if (nv < bnv[r]) { bnv[r] = nv; bnj[r] = jcol[s]; }
        }
    }

    // reduce across the 16 lanes of each row group (masks < 16 keep kg fixed)
    #pragma unroll
    for (int r = 0; r < 4; ++r) {
        #pragma unroll
        for (int m = 8; m > 0; m >>= 1) {
            const float opv = __shfl_xor(bpv[r], m); const int opj = __shfl_xor(bpj[r], m);
            if (opv > bpv[r] || (opv == bpv[r] && opj < bpj[r])) { bpv[r] = opv; bpj[r] = opj; }
            const float onv = __shfl_xor(bnv[r], m); const int onj = __shfl_xor(bnj[r], m);
            if (onv < bnv[r] || (onv == bnv[r] && onj < bnj[r])) { bnv[r] = onv; bnj[r] = onj; }
        }
    }

    // ---- cross-wave combine: 16 rows x 8 waves (ascending col ranges) ----
    __shared__ float L_pv[16][8]; __shared__ int L_pj[16][8];
    __shared__ float L_nv[16][8]; __shared__ int L_nj[16][8];
    if (l15 == 0) {
        #pragma unroll
        for (int r = 0; r < 4; ++r) {
            const int rib = kg * 4 + r;
            L_pv[rib][w] = bpv[r]; L_pj[rib][w] = bpj[r];
            L_nv[rib][w] = bnv[r]; L_nj[rib][w] = bnj[r];
        }
    }
    __syncthreads();

    if (t < 16) {
        float pv = -1.0f; int pj = 0x7fffffff; float nv = FLT_MAX; int nj = 0x7fffffff;
        #pragma unroll
        for (int c = 0; c < 8; ++c) {   // ascending cols -> tie keeps first
            const float v1 = L_pv[t][c]; const int j1 = L_pj[t][c];
            if (v1 > pv || (v1 == pv && j1 < pj)) { pv = v1; pj = j1; }
            const float v2 = L_nv[t][c]; const int j2 = L_nj[t][c];
            if (v2 < nv || (v2 == nv && j2 < nj)) { nv = v2; nj = j2; }
        }
        cand[(size_t)(RG * 4 + q) * 16 + t] =
            make_float4(pv, __int_as_float(pj), nv, __int_as_float(nj));
    }
}

// ---------------- Kernel C: merge 4 chunks/row + exact fp32 intra gather ----------------
// 128 blocks x 256 threads; 16 lanes per row, 16 rows per block.
__global__ __launch_bounds__(256) void finalize_kernel(
    const float* __restrict__ feat, const float4* __restrict__ cand,
    float* __restrict__ partial)
{
    const int t  = threadIdx.x;
    const int gr = blockIdx.x * 16 + (t >> 4);   // global row 0..2047
    const int sl = t & 15;
    const int half = gr >> 10;
    const int RG = gr >> 4, row16 = gr & 15;
    const float* fB = feat + (half ? 0 : BATCH * DIM);   // b-side features = f_intra

    float pv = -1.0f; int pj = 0x7fffffff; float nv = FLT_MAX; int nj = 0x7fffffff;
    #pragma unroll
    for (int c = 0; c < 4; ++c) {    // ascending col chunks -> tie keeps first
        const float4 e = cand[(size_t)(RG * 4 + c) * 16 + row16];
        const int ej = __float_as_int(e.y), en = __float_as_int(e.w);
        if (e.x > pv || (e.x == pv && ej < pj)) { pv = e.x; pj = ej; }
        if (e.z < nv || (e.z == nv && en < nj)) { nv = e.z; nj = en; }
    }
    pj = pj > (BATCH - 1) ? (BATCH - 1) : pj;   // safety (unreachable in practice)
    nj = nj > (BATCH - 1) ? (BATCH - 1) : nj;
    const float fp = (pv > 0.0f) ? sqrtf(pv + EPSV) : 0.0f;  // no-positive row -> 0
    const float cn = sqrtf(nv + EPSV);

    const float4* x = reinterpret_cast<const float4*>(fB + (size_t)pj * DIM + sl * 8);
    const float4* y = reinterpret_cast<const float4*>(fB + (size_t)nj * DIM + sl * 8);
    const float4 x0 = x[0], x1 = x[1], y0 = y[0], y1 = y[1];
    float d, d2;
    d = x0.x - y0.x; d2  = d * d;  d = x0.y - y0.y; d2 += d * d;
    d = x0.z - y0.z; d2 += d * d;  d = x0.w - y0.w; d2 += d * d;
    d = x1.x - y1.x; d2 += d * d;  d = x1.y - y1.y; d2 += d * d;
    d = x1.z - y1.z; d2 += d * d;  d = x1.w - y1.w; d2 += d * d;
    d2 += __shfl_xor(d2, 1); d2 += __shfl_xor(d2, 2);
    d2 += __shfl_xor(d2, 4); d2 += __shfl_xor(d2, 8);

    __shared__ float ls[16];
    if (sl == 0) {
        const float g = sqrtf(d2 + EPSV);
        const float loss = fmaxf(fp - cn + MARGIN, 0.0f) + LAMDA * fmaxf(INTRA_MARGIN - g, 0.0f);
        ls[t >> 4] = loss * (1.0f / (float)BATCH);
    }
    __syncthreads();
    if (t == 0) {
        float s = 0.0f;
        #pragma unroll
        for (int i = 0; i < 16; ++i) s += ls[i];
        partial[blockIdx.x] = s;
    }
}

// ---------------- Kernel D: deterministic reduce of 128 partials ----------------
__global__ __launch_bounds__(128) void reduce_kernel(
    const float* __restrict__ partial, float* __restrict__ out)
{
    const int t = threadIdx.x;
    float s = partial[t];
    #pragma unroll
    for (int m = 32; m > 0; m >>= 1) s += __shfl_down(s, m);
    __shared__ float ws2[2];
    if ((t & 63) == 0) ws2[t >> 6] = s;
    __syncthreads();
    if (t == 0) out[0] = ws2[0] + ws2[1];
}

extern "C" void kernel_launch(void* const* d_in, const int* in_sizes, int n_in,
                              void* d_out, int out_size, void* d_ws, size_t ws_size,
                              hipStream_t stream) {
    const float* feat   = (const float*)d_in[0];
    const int*   label1 = (const int*)d_in[1];
    const int*   label2 = (const int*)d_in[2];
    float* out = (float*)d_out;

    char* ws = (char*)d_ws;
    float*  partial = (float*)(ws);                            // 512 B
    float4* cand    = (float4*)(ws + 4096);                    // 128 KB
    ushort* bhi     = (ushort*)(ws + 4096 + 128 * 1024);       // 512 KB (swizzled)
    float*  norm2   = (float*)(ws + 4096 + 640 * 1024);        // 8 KB

    prep_kernel<<<dim3(128), dim3(256), 0, stream>>>(feat, bhi, norm2);
    gemm_kernel<<<dim3(512), dim3(512), 0, stream>>>(bhi, norm2, label1, label2, cand);
    finalize_kernel<<<dim3(128), dim3(256), 0, stream>>>(feat, cand, partial);
    reduce_kernel<<<dim3(1), dim3(128), 0, stream>>>(partial, out);
}

// Round 12
// 21.123 us; speedup vs baseline: 1.9319x; 1.1284x over previous
//
#include <hip/hip_runtime.h>
#include <math.h>
#include <float.h>

#define BATCH 1024
#define DIM 128
#define EPSV 1e-12f
#define MARGIN 0.5f
#define INTRA_MARGIN 0.1f
#define LAMDA 0.5f

typedef __attribute__((ext_vector_type(8))) short s16x8;   // 8 bf16 (4 VGPRs)
typedef __attribute__((ext_vector_type(4))) float f32x4;   // MFMA C/D

__device__ __forceinline__ ushort f2bf(float f) {          // RNE fp32 -> bf16
    unsigned u = __float_as_uint(f);
    return (ushort)((u + 0x7fffu + ((u >> 16) & 1u)) >> 16);
}

// async global->LDS, 16B per lane (dest = wave-uniform base + lane*16)
__device__ __forceinline__ void gl_lds16(const void* g, void* l) {
    __builtin_amdgcn_global_load_lds(
        (const __attribute__((address_space(1))) unsigned int*)g,
        (__attribute__((address_space(3))) unsigned int*)l,
        16, 0, 0);
}

#define WAITVM4()  do { asm volatile("s_waitcnt vmcnt(4)" ::: "memory"); __builtin_amdgcn_sched_barrier(0); } while (0)
#define WAITVM0()  do { asm volatile("s_waitcnt vmcnt(0)" ::: "memory"); __builtin_amdgcn_sched_barrier(0); } while (0)
#define WAITLGKM() do { asm volatile("s_waitcnt lgkmcnt(0)" ::: "memory"); __builtin_amdgcn_sched_barrier(0); } while (0)

// ---------------- Kernel A: feat -> bf16 (XOR-swizzled) + fp32 row norms ----------------
// Swizzle: 16B chunk j of row r stored at chunk index (j ^ (r&7)) within the row.
__global__ __launch_bounds__(256) void prep_kernel(
    const float* __restrict__ feat, ushort* __restrict__ bhi,
    float* __restrict__ norm2)
{
    const int t = threadIdx.x;
    const int gt  = blockIdx.x * 256 + t;  // 0..32767
    const int row = gt >> 4, seg = gt & 15;
    const float4* p = reinterpret_cast<const float4*>(feat + (size_t)row * DIM + seg * 8);
    const float4 a = p[0], b = p[1];
    const float v[8] = {a.x, a.y, a.z, a.w, b.x, b.y, b.z, b.w};
    ushort h[8];
    float n = 0.0f;
    #pragma unroll
    for (int e = 0; e < 8; ++e) {
        h[e] = f2bf(v[e]);
        n = fmaf(v[e], v[e], n);
    }
    uint4 uh;
    uh.x = (uint)h[0] | ((uint)h[1] << 16); uh.y = (uint)h[2] | ((uint)h[3] << 16);
    uh.z = (uint)h[4] | ((uint)h[5] << 16); uh.w = (uint)h[6] | ((uint)h[7] << 16);
    reinterpret_cast<uint4*>(bhi)[row * 16 + (seg ^ (row & 7))] = uh;   // swizzled chunk
    n += __shfl_xor(n, 1); n += __shfl_xor(n, 2);
    n += __shfl_xor(n, 4); n += __shfl_xor(n, 8);
    if ((t & 15) == 0) norm2[row] = n;
}

__device__ __forceinline__ void issue_chunk(const char* bbytes, size_t gbase,
                                            char* buf, int w, int lane) {
    #pragma unroll
    for (int i = 0; i < 4; ++i) {
        const int o = w * 4096 + i * 1024 + lane * 16;
        gl_lds16(bbytes + gbase + o, buf + o);
    }
}

// ---------------- Kernel B: pipelined LDS-staged MFMA gram + selection + intra ----------
// 256 blocks x 512 threads (1 block/CU). Block = 8 rows x ALL 1024 cols.
// 8 chunks of 128 cols; 2 x 32 KB LDS buffers; wave-local staging (wave w stages and
// reads only cols [w*16, w*16+16) of each chunk) -> NO barriers in the main loop.
// Counted vmcnt(4) keeps the next chunk's DMA in flight under compute (T3/T4).
__global__ __launch_bounds__(512, 2) void gemm_kernel(
    const ushort* __restrict__ bhi, const float* __restrict__ norm2,
    const float* __restrict__ feat,
    const int* __restrict__ label1, const int* __restrict__ label2,
    float* __restrict__ partial)
{
    __shared__ __align__(16) char smem[65536];   // [buf0 32KB][buf1 32KB]; reused after loop

    const int rg    = blockIdx.x;            // 0..255
    const int half  = rg >> 7;
    const int arow0 = (rg & 127) * 8;
    const int aglob0 = half * BATCH + arow0;
    const int bglob0 = (half ^ 1) * BATCH;

    const int t = threadIdx.x;
    const int w = t >> 6, lane = t & 63;
    const int l15 = lane & 15, kg = lane >> 4;

    const int* labA = half ? label2 : label1;
    const int* labB = half ? label1 : label2;

    // ---- scalar-side loads (complete under staging latency) ----
    float nb[8]; int lb[8];
    #pragma unroll
    for (int c = 0; c < 8; ++c) {
        const int jc = c * 128 + w * 16 + l15;
        nb[c] = norm2[bglob0 + jc];
        lb[c] = labB[jc];
    }
    float na[4]; int la[4];
    #pragma unroll
    for (int r = 0; r < 4; ++r) {
        const int rr = (kg * 4 + r) & 7;
        na[r] = norm2[aglob0 + rr];
        la[r] = labA[arow0 + rr];
    }

    // ---- A fragments from global (pre-swizzled addresses); rows duplicated via l15&7 ----
    s16x8 ah[4];
    const size_t abase = (size_t)(aglob0 + (l15 & 7)) * DIM;
    #pragma unroll
    for (int kt = 0; kt < 4; ++kt) {
        const int kh = (kt * 32 + kg * 8) ^ ((l15 & 7) << 3);
        ah[kt] = *reinterpret_cast<const s16x8*>(bhi + abase + kh);
    }

    // ---- prologue: DMA chunks 0,1 ----
    const char* bbytes = reinterpret_cast<const char*>(bhi);
    char* buf0 = smem;
    char* buf1 = smem + 32768;
    issue_chunk(bbytes, (size_t)(bglob0 + 0 * 128) * 256, buf0, w, lane);
    issue_chunk(bbytes, (size_t)(bglob0 + 1 * 128) * 256, buf1, w, lane);
    WAITVM4();                      // chunk0 (and all pre-loads) complete; chunk1 in flight

    float bpv[4], bnv[4]; int bpj[4], bnj[4];
    #pragma unroll
    for (int r = 0; r < 4; ++r) { bpv[r] = -1.0f; bpj[r] = 0x7fffffff; bnv[r] = FLT_MAX; bnj[r] = 0x7fffffff; }

    const int jl = w * 16 + l15;    // local col within chunk (wave-local region)
    const ushort* b0 = reinterpret_cast<const ushort*>(buf0);
    const ushort* b1 = reinterpret_cast<const ushort*>(buf1);

    #pragma unroll
    for (int c = 0; c < 8; ++c) {
        const ushort* bufc = (c & 1) ? b1 : b0;

        // ds_read the 4 B-fragments for this chunk (own wave's staged cols)
        s16x8 bh[4];
        #pragma unroll
        for (int kt = 0; kt < 4; ++kt) {
            const int kh = (kt * 32 + kg * 8) ^ ((l15 & 7) << 3);
            bh[kt] = *reinterpret_cast<const s16x8*>(bufc + jl * DIM + kh);
        }
        if (c < 6) {
            WAITLGKM();             // frags landed in VGPRs -> safe to overwrite buffer
            issue_chunk(bbytes, (size_t)(bglob0 + (c + 2) * 128) * 256,
                        (c & 1) ? buf1 : buf0, w, lane);
        }

        // MFMA (C/D: col=l15, row=kg*4+reg; rows>=8 duplicate rows 0..7)
        f32x4 acc = (f32x4){0.f, 0.f, 0.f, 0.f};
        #pragma unroll
        for (int kt = 0; kt < 4; ++kt)
            acc = __builtin_amdgcn_mfma_f32_16x16x32_bf16(ah[kt], bh[kt], acc, 0, 0, 0);

        // selection in d^2 domain; j = c*128 + jl ascending in c -> first occurrence kept
        const int jc = c * 128 + jl;
        #pragma unroll
        for (int r = 0; r < 4; ++r) {
            const float d2 = fmaxf(na[r] + nb[c] - 2.0f * acc[r], 0.0f);
            const bool same = (la[r] == lb[c]);
            const float pv = same ? d2 : 0.0f;
            const float nv = same ? FLT_MAX : d2;
            if (pv > bpv[r]) { bpv[r] = pv; bpj[r] = jc; }
            if (nv < bnv[r]) { bnv[r] = nv; bnj[r] = jc; }
        }

        if (c < 6)      WAITVM4();  // next chunk complete; the one after stays in flight
        else if (c == 6) WAITVM0(); // drain last chunk
    }

    // ---- in-wave reduce across the 16 lanes of each row group ----
    #pragma unroll
    for (int r = 0; r < 4; ++r) {
        #pragma unroll
        for (int m = 8; m > 0; m >>= 1) {
            const float opv = __shfl_xor(bpv[r], m); const int opj = __shfl_xor(bpj[r], m);
            if (opv > bpv[r] || (opv == bpv[r] && opj < bpj[r])) { bpv[r] = opv; bpj[r] = opj; }
            const float onv = __shfl_xor(bnv[r], m); const int onj = __shfl_xor(bnj[r], m);
            if (onv < bnv[r] || (onv == bnv[r] && onj < bnj[r])) { bnv[r] = onv; bnj[r] = onj; }
        }
    }

    __syncthreads();                // all waves done with LDS buffers -> reuse smem

    float (*L_pv)[8] = (float(*)[8])(smem);
    int   (*L_pj)[8] = (int  (*)[8])(smem + 512);
    float (*L_nv)[8] = (float(*)[8])(smem + 1024);
    int   (*L_nj)[8] = (int  (*)[8])(smem + 1536);
    int*   s_pp = (int*)  (smem + 2048);
    int*   s_pn = (int*)  (smem + 2112);
    float* s_fp = (float*)(smem + 2176);
    float* s_cn = (float*)(smem + 2240);
    float* ls   = (float*)(smem + 2304);

    if (l15 == 0) {
        #pragma unroll
        for (int r = 0; r < 4; ++r) {
            const int rib = kg * 4 + r;     // rows 8..15 duplicate 0..7 (ignored below)
            L_pv[rib][w] = bpv[r]; L_pj[rib][w] = bpj[r];
            L_nv[rib][w] = bnv[r]; L_nj[rib][w] = bnj[r];
        }
    }
    __syncthreads();

    if (t < 8) {                    // merge 8 waves for the 8 real rows (tie-break on j)
        float pv = -1.0f; int pj = 0x7fffffff; float nv = FLT_MAX; int nj = 0x7fffffff;
        #pragma unroll
        for (int c = 0; c < 8; ++c) {
            const float v1 = L_pv[t][c]; const int j1 = L_pj[t][c];
            if (v1 > pv || (v1 == pv && j1 < pj)) { pv = v1; pj = j1; }
            const float v2 = L_nv[t][c]; const int j2 = L_nj[t][c];
            if (v2 < nv || (v2 == nv && j2 < nj)) { nv = v2; nj = j2; }
        }
        s_pp[t] = pj > (BATCH - 1) ? (BATCH - 1) : pj;
        s_pn[t] = nj > (BATCH - 1) ? (BATCH - 1) : nj;
        s_fp[t] = (pv > 0.0f) ? sqrtf(pv + EPSV) : 0.0f;   // no-positive row -> 0
        s_cn[t] = sqrtf(nv + EPSV);
    }
    __syncthreads();

    // ---- intra distances (exact fp32): 8 rows x 16 lanes ----
    if (t < 128) {
        const int g = t >> 4, sl = t & 15;
        const float* fB = feat + (size_t)(half ^ 1) * BATCH * DIM;  // b-side = f_intra
        const float4* x = reinterpret_cast<const float4*>(fB + (size_t)s_pp[g] * DIM + sl * 8);
        const float4* y = reinterpret_cast<const float4*>(fB + (size_t)s_pn[g] * DIM + sl * 8);
        const float4 x0 = x[0], x1 = x[1], y0 = y[0], y1 = y[1];
        float d, d2;
        d = x0.x - y0.x; d2  = d * d;  d = x0.y - y0.y; d2 += d * d;
        d = x0.z - y0.z; d2 += d * d;  d = x0.w - y0.w; d2 += d * d;
        d = x1.x - y1.x; d2 += d * d;  d = x1.y - y1.y; d2 += d * d;
        d = x1.z - y1.z; d2 += d * d;  d = x1.w - y1.w; d2 += d * d;
        d2 += __shfl_xor(d2, 1); d2 += __shfl_xor(d2, 2);
        d2 += __shfl_xor(d2, 4); d2 += __shfl_xor(d2, 8);
        if (sl == 0) {
            const float gd = sqrtf(d2 + EPSV);
            const float loss = fmaxf(s_fp[g] - s_cn[g] + MARGIN, 0.0f)
                             + LAMDA * fmaxf(INTRA_MARGIN - gd, 0.0f);
            ls[g] = loss * (1.0f / (float)BATCH);
        }
    }
    __syncthreads();

    if (t == 0) {
        float s = 0.0f;
        #pragma unroll
        for (int i = 0; i < 8; ++i) s += ls[i];
        partial[rg] = s;
    }
}

// ---------------- Kernel C: deterministic reduce of 256 partials ----------------
__global__ __launch_bounds__(256) void reduce_kernel(
    const float* __restrict__ partial, float* __restrict__ out)
{
    const int t = threadIdx.x;
    float s = partial[t];
    #pragma unroll
    for (int m = 32; m > 0; m >>= 1) s += __shfl_down(s, m);
    __shared__ float ws4[4];
    if ((t & 63) == 0) ws4[t >> 6] = s;
    __syncthreads();
    if (t == 0) out[0] = ws4[0] + ws4[1] + ws4[2] + ws4[3];
}

extern "C" void kernel_launch(void* const* d_in, const int* in_sizes, int n_in,
                              void* d_out, int out_size, void* d_ws, size_t ws_size,
                              hipStream_t stream) {
    const float* feat   = (const float*)d_in[0];
    const int*   label1 = (const int*)d_in[1];
    const int*   label2 = (const int*)d_in[2];
    float* out = (float*)d_out;

    char* ws = (char*)d_ws;
    float*  partial = (float*)(ws);                        // 1 KB
    ushort* bhi     = (ushort*)(ws + 4096);                // 512 KB (pre-swizzled)
    float*  norm2   = (float*)(ws + 4096 + 512 * 1024);    // 8 KB

    prep_kernel<<<dim3(128), dim3(256), 0, stream>>>(feat, bhi, norm2);
    gemm_kernel<<<dim3(256), dim3(512), 0, stream>>>(
        bhi, norm2, feat, label1, label2, partial);
    reduce_kernel<<<dim3(1), dim3(256), 0, stream>>>(partial, out);
}

// Round 13
// 21.067 us; speedup vs baseline: 1.9370x; 1.0027x over previous
//
#include <hip/hip_runtime.h>
#include <math.h>
#include <float.h>

#define BATCH 1024
#define DIM 128
#define EPSV 1e-12f
#define MARGIN 0.5f
#define INTRA_MARGIN 0.1f
#define LAMDA 0.5f

typedef __attribute__((ext_vector_type(8))) short s16x8;   // 8 bf16 (4 VGPRs)
typedef __attribute__((ext_vector_type(4))) float f32x4;   // MFMA C/D

__device__ __forceinline__ ushort f2bf(float f) {          // RNE fp32 -> bf16
    unsigned u = __float_as_uint(f);
    return (ushort)((u + 0x7fffu + ((u >> 16) & 1u)) >> 16);
}

// async global->LDS, 16B per lane (dest = wave-uniform base + lane*16)
__device__ __forceinline__ void gl_lds16(const void* g, void* l) {
    __builtin_amdgcn_global_load_lds(
        (const __attribute__((address_space(1))) unsigned int*)g,
        (__attribute__((address_space(3))) unsigned int*)l,
        16, 0, 0);
}

#define WAITVM8()  do { asm volatile("s_waitcnt vmcnt(8)" ::: "memory"); __builtin_amdgcn_sched_barrier(0); } while (0)
#define WAITVM4()  do { asm volatile("s_waitcnt vmcnt(4)" ::: "memory"); __builtin_amdgcn_sched_barrier(0); } while (0)
#define WAITVM0()  do { asm volatile("s_waitcnt vmcnt(0)" ::: "memory"); __builtin_amdgcn_sched_barrier(0); } while (0)

// ---------------- Kernel A: feat -> bf16 (XOR-swizzled) + fp32 row norms ----------------
// Swizzle: 16B chunk j of row r stored at chunk index (j ^ (r&7)) within the row.
__global__ __launch_bounds__(256) void prep_kernel(
    const float* __restrict__ feat, ushort* __restrict__ bhi,
    float* __restrict__ norm2)
{
    const int t = threadIdx.x;
    const int gt  = blockIdx.x * 256 + t;  // 0..32767
    const int row = gt >> 4, seg = gt & 15;
    const float4* p = reinterpret_cast<const float4*>(feat + (size_t)row * DIM + seg * 8);
    const float4 a = p[0], b = p[1];
    const float v[8] = {a.x, a.y, a.z, a.w, b.x, b.y, b.z, b.w};
    ushort h[8];
    float n = 0.0f;
    #pragma unroll
    for (int e = 0; e < 8; ++e) {
        h[e] = f2bf(v[e]);
        n = fmaf(v[e], v[e], n);
    }
    uint4 uh;
    uh.x = (uint)h[0] | ((uint)h[1] << 16); uh.y = (uint)h[2] | ((uint)h[3] << 16);
    uh.z = (uint)h[4] | ((uint)h[5] << 16); uh.w = (uint)h[6] | ((uint)h[7] << 16);
    reinterpret_cast<uint4*>(bhi)[row * 16 + (seg ^ (row & 7))] = uh;   // swizzled chunk
    n += __shfl_xor(n, 1); n += __shfl_xor(n, 2);
    n += __shfl_xor(n, 4); n += __shfl_xor(n, 8);
    if ((t & 15) == 0) norm2[row] = n;
}

__device__ __forceinline__ void issue_chunk(const char* bbytes, size_t gbase,
                                            char* buf, int w, int lane) {
    #pragma unroll
    for (int i = 0; i < 4; ++i) {
        const int o = w * 4096 + i * 1024 + lane * 16;
        gl_lds16(bbytes + gbase + o, buf + o);
    }
}

// ---------------- Kernel B: deep-pipelined LDS-staged MFMA gram + selection + intra ----
// 256 blocks x 512 threads (1 block/CU, 128 KB LDS). Block = 8 rows x ALL 1024 cols.
// 8 chunks of 128 cols; 4 x 32 KB LDS ring; wave-local staging (wave w stages and reads
// only cols [w*16, +16) of each chunk) -> NO barriers, NO lgkm guard (overwrite target
// is 4 chunks old; compiler's lgkmcnt waits before the MFMAs already drained its reads).
// Counted vmcnt(8): 2-3 chunks in flight, ~2 iterations of latency cover (T3/T4).
__global__ __launch_bounds__(512, 1) void gemm_kernel(
    const ushort* __restrict__ bhi, const float* __restrict__ norm2,
    const float* __restrict__ feat,
    const int* __restrict__ label1, const int* __restrict__ label2,
    float* __restrict__ partial)
{
    __shared__ __align__(16) char smem[131072];  // 4 x 32 KB ring; reused after loop

    const int rg    = blockIdx.x;            // 0..255
    const int half  = rg >> 7;
    const int arow0 = (rg & 127) * 8;
    const int aglob0 = half * BATCH + arow0;
    const int bglob0 = (half ^ 1) * BATCH;

    const int t = threadIdx.x;
    const int w = t >> 6, lane = t & 63;
    const int l15 = lane & 15, kg = lane >> 4;

    const int* labA = half ? label2 : label1;
    const int* labB = half ? label1 : label2;

    // ---- scalar-side loads (retire before the prologue vmcnt wait) ----
    float nb[8]; int lb[8];
    #pragma unroll
    for (int c = 0; c < 8; ++c) {
        const int jc = c * 128 + w * 16 + l15;
        nb[c] = norm2[bglob0 + jc];
        lb[c] = labB[jc];
    }
    float na[4]; int la[4];
    #pragma unroll
    for (int r = 0; r < 4; ++r) {
        const int rr = (kg * 4 + r) & 7;
        na[r] = norm2[aglob0 + rr];
        la[r] = labA[arow0 + rr];
    }

    // ---- A fragments from global (pre-swizzled addresses); rows duplicated via l15&7 ----
    s16x8 ah[4];
    const size_t abase = (size_t)(aglob0 + (l15 & 7)) * DIM;
    #pragma unroll
    for (int kt = 0; kt < 4; ++kt) {
        const int kh = (kt * 32 + kg * 8) ^ ((l15 & 7) << 3);
        ah[kt] = *reinterpret_cast<const s16x8*>(bhi + abase + kh);
    }

    // ---- prologue: DMA chunks 0,1,2 into ring slots 0,1,2 ----
    const char* bbytes = reinterpret_cast<const char*>(bhi);
    issue_chunk(bbytes, (size_t)(bglob0 + 0 * 128) * 256, smem + 0 * 32768, w, lane);
    issue_chunk(bbytes, (size_t)(bglob0 + 1 * 128) * 256, smem + 1 * 32768, w, lane);
    issue_chunk(bbytes, (size_t)(bglob0 + 2 * 128) * 256, smem + 2 * 32768, w, lane);
    WAITVM8();                      // scalars+A+chunk0 retired; chunks 1,2 in flight

    float bpv[4], bnv[4]; int bpj[4], bnj[4];
    #pragma unroll
    for (int r = 0; r < 4; ++r) { bpv[r] = -1.0f; bpj[r] = 0x7fffffff; bnv[r] = FLT_MAX; bnj[r] = 0x7fffffff; }

    const int jl = w * 16 + l15;    // local col within chunk (wave-local region)

    #pragma unroll
    for (int c = 0; c < 8; ++c) {
        const ushort* bufc = reinterpret_cast<const ushort*>(smem + (c & 3) * 32768);

        // ds_read the 4 B-fragments for this chunk (own wave's staged cols)
        s16x8 bh[4];
        #pragma unroll
        for (int kt = 0; kt < 4; ++kt) {
            const int kh = (kt * 32 + kg * 8) ^ ((l15 & 7) << 3);
            bh[kt] = *reinterpret_cast<const s16x8*>(bufc + jl * DIM + kh);
        }
        if (c <= 4)                 // prefetch chunk c+3 into slot (c+3)&3 (= chunk c-1's)
            issue_chunk(bbytes, (size_t)(bglob0 + (c + 3) * 128) * 256,
                        smem + ((c + 3) & 3) * 32768, w, lane);

        // MFMA (C/D: col=l15, row=kg*4+reg; rows>=8 duplicate rows 0..7)
        f32x4 acc = (f32x4){0.f, 0.f, 0.f, 0.f};
        #pragma unroll
        for (int kt = 0; kt < 4; ++kt)
            acc = __builtin_amdgcn_mfma_f32_16x16x32_bf16(ah[kt], bh[kt], acc, 0, 0, 0);

        // selection in d^2 domain; j = c*128 + jl ascending in c -> first occurrence kept
        const int jc = c * 128 + jl;
        #pragma unroll
        for (int r = 0; r < 4; ++r) {
            const float d2 = fmaxf(na[r] + nb[c] - 2.0f * acc[r], 0.0f);
            const bool same = (la[r] == lb[c]);
            const float pv = same ? d2 : 0.0f;
            const float nv = same ? FLT_MAX : d2;
            if (pv > bpv[r]) { bpv[r] = pv; bpj[r] = jc; }
            if (nv < bnv[r]) { bnv[r] = nv; bnj[r] = jc; }
        }

        // retire the next chunk's DMA: end of iter c -> chunk c+1 complete
        if (c <= 4)      WAITVM8();
        else if (c == 5) WAITVM4();
        else if (c == 6) WAITVM0();
    }

    // ---- in-wave reduce across the 16 lanes of each row group ----
    #pragma unroll
    for (int r = 0; r < 4; ++r) {
        #pragma unroll
        for (int m = 8; m > 0; m >>= 1) {
            const float opv = __shfl_xor(bpv[r], m); const int opj = __shfl_xor(bpj[r], m);
            if (opv > bpv[r] || (opv == bpv[r] && opj < bpj[r])) { bpv[r] = opv; bpj[r] = opj; }
            const float onv = __shfl_xor(bnv[r], m); const int onj = __shfl_xor(bnj[r], m);
            if (onv < bnv[r] || (onv == bnv[r] && onj < bnj[r])) { bnv[r] = onv; bnj[r] = onj; }
        }
    }

    __syncthreads();                // all waves done with LDS ring -> reuse smem

    float (*L_pv)[8] = (float(*)[8])(smem);
    int   (*L_pj)[8] = (int  (*)[8])(smem + 512);
    float (*L_nv)[8] = (float(*)[8])(smem + 1024);
    int   (*L_nj)[8] = (int  (*)[8])(smem + 1536);
    int*   s_pp = (int*)  (smem + 2048);
    int*   s_pn = (int*)  (smem + 2112);
    float* s_fp = (float*)(smem + 2176);
    float* s_cn = (float*)(smem + 2240);
    float* ls   = (float*)(smem + 2304);

    if (l15 == 0) {
        #pragma unroll
        for (int r = 0; r < 4; ++r) {
            const int rib = kg * 4 + r;     // rows 8..15 duplicate 0..7 (ignored below)
            L_pv[rib][w] = bpv[r]; L_pj[rib][w] = bpj[r];
            L_nv[rib][w] = bnv[r]; L_nj[rib][w] = bnj[r];
        }
    }
    __syncthreads();

    if (t < 8) {                    // merge 8 waves for the 8 real rows (tie-break on j)
        float pv = -1.0f; int pj = 0x7fffffff; float nv = FLT_MAX; int nj = 0x7fffffff;
        #pragma unroll
        for (int c = 0; c < 8; ++c) {
            const float v1 = L_pv[t][c]; const int j1 = L_pj[t][c];
            if (v1 > pv || (v1 == pv && j1 < pj)) { pv = v1; pj = j1; }
            const float v2 = L_nv[t][c]; const int j2 = L_nj[t][c];
            if (v2 < nv || (v2 == nv && j2 < nj)) { nv = v2; nj = j2; }
        }
        s_pp[t] = pj > (BATCH - 1) ? (BATCH - 1) : pj;
        s_pn[t] = nj > (BATCH - 1) ? (BATCH - 1) : nj;
        s_fp[t] = (pv > 0.0f) ? sqrtf(pv + EPSV) : 0.0f;   // no-positive row -> 0
        s_cn[t] = sqrtf(nv + EPSV);
    }
    __syncthreads();

    // ---- intra distances (exact fp32): 8 rows x 16 lanes ----
    if (t < 128) {
        const int g = t >> 4, sl = t & 15;
        const float* fB = feat + (size_t)(half ^ 1) * BATCH * DIM;  // b-side = f_intra
        const float4* x = reinterpret_cast<const float4*>(fB + (size_t)s_pp[g] * DIM + sl * 8);
        const float4* y = reinterpret_cast<const float4*>(fB + (size_t)s_pn[g] * DIM + sl * 8);
        const float4 x0 = x[0], x1 = x[1], y0 = y[0], y1 = y[1];
        float d, d2;
        d = x0.x - y0.x; d2  = d * d;  d = x0.y - y0.y; d2 += d * d;
        d = x0.z - y0.z; d2 += d * d;  d = x0.w - y0.w; d2 += d * d;
        d = x1.x - y1.x; d2 += d * d;  d = x1.y - y1.y; d2 += d * d;
        d = x1.z - y1.z; d2 += d * d;  d = x1.w - y1.w; d2 += d * d;
        d2 += __shfl_xor(d2, 1); d2 += __shfl_xor(d2, 2);
        d2 += __shfl_xor(d2, 4); d2 += __shfl_xor(d2, 8);
        if (sl == 0) {
            const float gd = sqrtf(d2 + EPSV);
            const float loss = fmaxf(s_fp[g] - s_cn[g] + MARGIN, 0.0f)
                             + LAMDA * fmaxf(INTRA_MARGIN - gd, 0.0f);
            ls[g] = loss * (1.0f / (float)BATCH);
        }
    }
    __syncthreads();

    if (t == 0) {
        float s = 0.0f;
        #pragma unroll
        for (int i = 0; i < 8; ++i) s += ls[i];
        partial[rg] = s;
    }
}

// ---------------- Kernel C: single-wave deterministic reduce of 256 partials ----------
__global__ __launch_bounds__(64) void reduce_kernel(
    const float* __restrict__ partial, float* __restrict__ out)
{
    const int t = threadIdx.x;
    float s = partial[t] + partial[t + 64] + partial[t + 128] + partial[t + 192];
    #pragma unroll
    for (int m = 32; m > 0; m >>= 1) s += __shfl_down(s, m);
    if (t == 0) out[0] = s;
}

extern "C" void kernel_launch(void* const* d_in, const int* in_sizes, int n_in,
                              void* d_out, int out_size, void* d_ws, size_t ws_size,
                              hipStream_t stream) {
    const float* feat   = (const float*)d_in[0];
    const int*   label1 = (const int*)d_in[1];
    const int*   label2 = (const int*)d_in[2];
    float* out = (float*)d_out;

    char* ws = (char*)d_ws;
    float*  partial = (float*)(ws);                        // 1 KB
    ushort* bhi     = (ushort*)(ws + 4096);                // 512 KB (pre-swizzled)
    float*  norm2   = (float*)(ws + 4096 + 512 * 1024);    // 8 KB

    prep_kernel<<<dim3(128), dim3(256), 0, stream>>>(feat, bhi, norm2);
    gemm_kernel<<<dim3(256), dim3(512), 0, stream>>>(
        bhi, norm2, feat, label1, label2, partial);
    reduce_kernel<<<dim3(1), dim3(64), 0, stream>>>(partial, out);
}